// Round 18
// baseline (203.038 us; speedup 1.0000x reference)
//
#include <hip/hip_runtime.h>

typedef _Float16 f16;
typedef __attribute__((ext_vector_type(2))) _Float16 f16x2;
typedef __attribute__((ext_vector_type(4))) _Float16 f16x4;
typedef __attribute__((ext_vector_type(8))) _Float16 f16x8;
typedef __attribute__((ext_vector_type(4))) float fvec4;
typedef __attribute__((ext_vector_type(4))) float f32x4;
typedef __attribute__((ext_vector_type(16))) float f32x16;
typedef __attribute__((ext_vector_type(4))) unsigned int uint4v;

#define NKEY 784
#define NKEYP 800
#define NQ 196
#define NQP 224
#define LOG2E 1.442695041f
#define SC2   0.360673760f   /* 0.25 * log2(e) */
#define THR2  11.5415603f    /* 8 * log2(e) */

static __device__ __forceinline__ f32x4 mfma16(f16x8 a, f16x8 b, f32x4 c) {
    return __builtin_amdgcn_mfma_f32_16x16x32_f16(a, b, c, 0, 0, 0);
}
static __device__ __forceinline__ f32x16 mfma32(f16x8 a, f16x8 b, f32x16 c) {
    return __builtin_amdgcn_mfma_f32_32x32x16_f16(a, b, c, 0, 0, 0);
}
static __device__ __forceinline__ unsigned pkrtz(float a, float b) {
    return __builtin_bit_cast(unsigned, __builtin_amdgcn_cvt_pkrtz(a, b));
}
static __device__ __forceinline__ f32x16 z16() {
    f32x16 v;
#pragma unroll
    for (int i = 0; i < 16; ++i) v[i] = 0.f;
    return v;
}

// ---------------- merged prep: BN scales | W->f16 k-major | bias gather | q-pad zero ----------------
__global__ void prep_all(const float* __restrict__ kg, const float* __restrict__ kbet,
                         const float* __restrict__ km, const float* __restrict__ kvv,
                         const float* __restrict__ qg, const float* __restrict__ qbet,
                         const float* __restrict__ qm, const float* __restrict__ qv,
                         const float* __restrict__ pg, const float* __restrict__ pbet,
                         const float* __restrict__ pm, const float* __restrict__ pv,
                         const float* __restrict__ wkv, const float* __restrict__ wq,
                         const float* __restrict__ wp, const float* __restrict__ biases,
                         const int* __restrict__ idxs, int n_off,
                         float* __restrict__ sb, f16* __restrict__ wf16,
                         f16* __restrict__ biasS, f16* __restrict__ qbuf) {
    const int blk = blockIdx.x;
    const int t = threadIdx.x;
    if (blk < 5) {                                    // BN scale/shift folding
        int i = blk * 256 + t;
        if (i < 640) {
            float s = kg[i] * rsqrtf(kvv[i] + 1e-5f);
            sb[i] = s; sb[640 + i] = kbet[i] - km[i] * s;
        } else if (i < 768) {
            int j = i - 640;
            float s = qg[j] * rsqrtf(qv[j] + 1e-5f);
            sb[1280 + j] = s * SC2;                   // q pre-scaled: logits in log2 units
            sb[1408 + j] = (qbet[j] - qm[j] * s) * SC2;
        } else if (i < 1152) {
            int j = i - 768;
            float s = pg[j] * rsqrtf(pv[j] + 1e-5f);
            sb[1536 + j] = s; sb[1920 + j] = pbet[j] - pm[j] * s;
        }
    } else if (blk < 197) {                           // weights -> f16, k-major fragments
        int i = (blk - 5) * 256 + t;                  // 49152 threads
        const float* src;
        f16* dst;
        int kc, n, K;
        if (i < 20480)      { int j = i;         kc = j / 640, n = j - kc * 640; src = wkv; dst = wf16 + (size_t)j * 8;          K = 256; }
        else if (i < 24576) { int j = i - 20480; kc = j / 128, n = j - kc * 128; src = wq;  dst = wf16 + 163840 + (size_t)j * 8; K = 256; }
        else                { int j = i - 24576; kc = j / 384, n = j - kc * 384; src = wp;  dst = wf16 + 196608 + (size_t)j * 8; K = 512; }
        const float* s = src + (size_t)n * K + kc * 8;
        fvec4 v0 = *(const fvec4*)s;
        fvec4 v1 = *(const fvec4*)(s + 4);
        f16x8 h;
        h[0] = (f16)v0[0]; h[1] = (f16)v0[1]; h[2] = (f16)v0[2]; h[3] = (f16)v0[3];
        h[4] = (f16)v1[0]; h[5] = (f16)v1[1]; h[6] = (f16)v1[2]; h[7] = (f16)v1[3];
        *(f16x8*)dst = h;
    } else if (blk < 5797) {                          // bias f16, lane-ordered, log2 domain
        int tid = (blk - 197) * 256 + t;              // 1,433,600 threads
        const int r = tid & 15;
        const int lane = (tid >> 4) & 63;
        const int g = tid >> 10;                      // [h][qt][kb]
        const int kbk = g % 25;
        const int tmp = g / 25;
        const int qt = tmp % 7;
        const int h = tmp / 7;
        const int q = qt * 32 + (lane & 31);
        const int key = kbk * 32 + (r & 3) + 8 * (r >> 2) + 4 * (lane >> 5);
        float v;
        if (key >= NKEY)  v = -30000.f;
        else if (q < NQ)  v = biases[h * n_off + idxs[q * NKEY + key]] * LOG2E;
        else              v = 0.f;
        biasS[tid] = (f16)v;
    } else {                                          // zero q buffer (pad rows)
        int idx = (blk - 5797) * 256 + t;             // 458,752 threads x 8 f16
        f16x8 zz;
#pragma unroll
        for (int j = 0; j < 8; ++j) zz[j] = (f16)0.f;
        *(f16x8*)(qbuf + (size_t)idx * 8) = zz;
    }
}

// ---------------- kv GEMM: 256 thr, MF=2 (wave = 32 rows), BM=128, W dbuf in LDS ----------------
// Each LDS B-fragment read feeds 2 MFMAs -> LDS bandwidth per output halves vs 512-thr.
__global__ __launch_bounds__(256) void gemm_kv(
        const float* __restrict__ Ap, const f16x8* __restrict__ Wg,
        const float* __restrict__ sc, const float* __restrict__ sh,
        f16* __restrict__ OutK, f16* __restrict__ OutV) {
    __shared__ f16x8 Wl[2][1024];                     // 2 x 16 KB

    const int t = threadIdx.x;
    const int lane = t & 63, wid = t >> 6;
    const int fr = lane & 15, kg = lane >> 4;
    const int m0 = blockIdx.x * 128;
    const int wrow0 = m0 + wid * 32;

    // ---- A fragments: 2 x 16 rows per wave ----
    f16x8 af[2][8];
#pragma unroll
    for (int mf = 0; mf < 2; ++mf) {
        const float* abase = Ap + (size_t)(wrow0 + mf * 16 + fr) * 256 + kg * 8;
#pragma unroll
        for (int ks = 0; ks < 8; ++ks) {
            fvec4 v0 = *(const fvec4*)(abase + ks * 32);
            fvec4 v1 = *(const fvec4*)(abase + ks * 32 + 4);
            f16x8 hv;
            hv[0] = (f16)v0[0]; hv[1] = (f16)v0[1]; hv[2] = (f16)v0[2]; hv[3] = (f16)v0[3];
            hv[4] = (f16)v1[0]; hv[5] = (f16)v1[1]; hv[6] = (f16)v1[2]; hv[7] = (f16)v1[3];
            af[mf][ks] = hv;
        }
    }

    // ---- prologue: stage chunk 0 (SR=4) ----
#pragma unroll
    for (int rr = 0; rr < 4; ++rr) {
        const int idx = rr * 256 + t;
        Wl[0][idx] = Wg[(size_t)(idx >> 5) * 640 + (idx & 31)];
    }
    __syncthreads();

    const int rg = kg * 4;
    int cur = 0;
    for (int c = 0; c < 20; ++c) {
        const int n0c = c * 32;

        f16x8 nx0, nx1, nx2, nx3;
        if (c + 1 < 20) {
            const int n0n = n0c + 32;
            nx0 = Wg[(size_t)((0 * 256 + t) >> 5) * 640 + n0n + (t & 31)];
            nx1 = Wg[(size_t)((1 * 256 + t) >> 5) * 640 + n0n + (t & 31)];
            nx2 = Wg[(size_t)((2 * 256 + t) >> 5) * 640 + n0n + (t & 31)];
            nx3 = Wg[(size_t)((3 * 256 + t) >> 5) * 640 + n0n + (t & 31)];
        }

        f32x4 acc[2][2];
#pragma unroll
        for (int i = 0; i < 2; ++i)
#pragma unroll
            for (int j = 0; j < 2; ++j) acc[i][j] = (f32x4){0.f, 0.f, 0.f, 0.f};
#pragma unroll
        for (int ks = 0; ks < 8; ++ks) {
            f16x8 b0 = Wl[cur][(ks * 4 + kg) * 32 + fr];
            f16x8 b1 = Wl[cur][(ks * 4 + kg) * 32 + 16 + fr];
            acc[0][0] = mfma16(af[0][ks], b0, acc[0][0]);
            acc[0][1] = mfma16(af[0][ks], b1, acc[0][1]);
            acc[1][0] = mfma16(af[1][ks], b0, acc[1][0]);
            acc[1][1] = mfma16(af[1][ks], b1, acc[1][1]);
        }

#pragma unroll
        for (int mf = 0; mf < 2; ++mf) {
            const int mbase = wrow0 + mf * 16 + rg;   // 4 consecutive rows, one b
#pragma unroll
            for (int nf = 0; nf < 2; ++nf) {
                const f32x4 a4 = acc[mf][nf];
                const int n = n0c + nf * 16 + fr;
                const float scn = sc[n], shn = sh[n];
                const int b = mbase / 784;
                const int nn = mbase - b * 784;
                const int hd = n / 80;
                const int cc = n - hd * 80;
                const size_t bh = (size_t)(b * 8 + hd);
                if (cc < 16) {
#pragma unroll
                    for (int r = 0; r < 4; ++r) {
                        float y = a4[r] * scn + shn;
                        OutK[(bh * NKEYP + nn + r) * 16 + cc] = (f16)y;
                    }
                } else {
                    // V layout [bh][kb][sH][d(64)][slot16]; slot = quartet-swap of key%16
                    const int kbk = nn >> 5, sH = (nn >> 4) & 1;
                    const int kq = (nn >> 2) & 3;
                    const int slot = ((((kq & 1) << 1) | (kq >> 1)) << 2) | (nn & 3);
                    f16x4 pv;
#pragma unroll
                    for (int r = 0; r < 4; ++r) pv[r] = (f16)(a4[r] * scn + shn);
                    *(f16x4*)(OutV + ((bh * 25 + kbk) * 2 + sH) * 1024 + (cc - 16) * 16 + slot) = pv;
                }
            }
        }

        if (c + 1 < 20) {
            Wl[cur ^ 1][0 * 256 + t] = nx0;
            Wl[cur ^ 1][1 * 256 + t] = nx1;
            Wl[cur ^ 1][2 * 256 + t] = nx2;
            Wl[cur ^ 1][3 * 256 + t] = nx3;
            __syncthreads();
            cur ^= 1;
        }
    }
}

// ---------------- small GEMMs (q / proj): A in registers, W db in LDS ----------------
// MODE 1: q : CHUNK=32, grid(392,1).  MODE 2: proj : CHUNK=16 (K=512), grid(392,2)
template <int MODE>
__global__ __launch_bounds__(256) void gemm_db(
        const void* __restrict__ Ap, const f16x8* __restrict__ Wg,
        const float* __restrict__ sc, const float* __restrict__ sh,
        void* __restrict__ OutA) {
    constexpr int K     = (MODE == 2) ? 512 : 256;
    constexpr int KS    = K / 32;
    constexpr int CHUNK = (MODE == 2) ? 16 : 32;
    constexpr int NFR   = CHUNK / 16;
    constexpr int NT    = (MODE == 1) ? 128 : 384;
    constexpr int NCH   = (MODE == 1) ? 4 : 12;
    constexpr int UNITS = (K / 8) * CHUNK;
    constexpr int SR    = UNITS / 256;

    __shared__ f16x8 Wl[2][UNITS];

    const int t = threadIdx.x;
    const int lane = t & 63, wid = t >> 6;
    const int fr = lane & 15, kg = lane >> 4;
    const int m0 = blockIdx.x * 64;
    const int nb0 = blockIdx.y * (NCH * CHUNK);
    const int mrow = m0 + wid * 16 + fr;

    size_t arow;
    if constexpr (MODE == 1) {
        int b = mrow / 196, nn = mrow - b * 196;
        arow = (size_t)b * 784 + (nn / 14) * 56 + (nn % 14) * 2;
    } else {
        arow = (size_t)mrow;
    }
    f16x8 af[KS];
#pragma unroll
    for (int ks = 0; ks < KS; ++ks) {
        if constexpr (MODE == 2) {
            af[ks] = *(const f16x8*)((const f16*)Ap + arow * K + ks * 32 + kg * 8);
        } else {
            const float* a = (const float*)Ap + arow * 256 + ks * 32 + kg * 8;
            fvec4 v0 = *(const fvec4*)a;
            fvec4 v1 = *(const fvec4*)(a + 4);
            f16x8 hv;
            hv[0] = (f16)v0[0]; hv[1] = (f16)v0[1]; hv[2] = (f16)v0[2]; hv[3] = (f16)v0[3];
            hv[4] = (f16)v1[0]; hv[5] = (f16)v1[1]; hv[6] = (f16)v1[2]; hv[7] = (f16)v1[3];
            af[ks] = hv;
        }
    }

#pragma unroll
    for (int rr = 0; rr < SR; ++rr) {
        const int idx = rr * 256 + t;
        Wl[0][idx] = Wg[(size_t)(idx / CHUNK) * NT + nb0 + (idx % CHUNK)];
    }
    __syncthreads();

    const int rg = kg * 4;
    int cur = 0;
    for (int c = 0; c < NCH; ++c) {
        const int n0c = nb0 + c * CHUNK;

        f16x8 nx0, nx1, nx2, nx3;
        if (c + 1 < NCH) {
            const int n0n = n0c + CHUNK;
            nx0 = Wg[(size_t)((0 * 256 + t) / CHUNK) * NT + n0n + ((0 * 256 + t) % CHUNK)];
            if constexpr (SR > 1)
                nx1 = Wg[(size_t)((1 * 256 + t) / CHUNK) * NT + n0n + ((1 * 256 + t) % CHUNK)];
            if constexpr (SR > 2) {
                nx2 = Wg[(size_t)((2 * 256 + t) / CHUNK) * NT + n0n + ((2 * 256 + t) % CHUNK)];
                nx3 = Wg[(size_t)((3 * 256 + t) / CHUNK) * NT + n0n + ((3 * 256 + t) % CHUNK)];
            }
        }

        f32x4 acc[NFR];
#pragma unroll
        for (int j = 0; j < NFR; ++j) acc[j] = (f32x4){0.f, 0.f, 0.f, 0.f};
#pragma unroll
        for (int ks = 0; ks < KS; ++ks) {
            f16x8 bfr[NFR];
#pragma unroll
            for (int nf = 0; nf < NFR; ++nf)
                bfr[nf] = Wl[cur][(ks * 4 + kg) * CHUNK + nf * 16 + fr];
#pragma unroll
            for (int nf = 0; nf < NFR; ++nf)
                acc[nf] = mfma16(af[ks], bfr[nf], acc[nf]);
        }

        const int mbase = m0 + wid * 16 + rg;
#pragma unroll
        for (int nf = 0; nf < NFR; ++nf) {
            const int n = n0c + nf * 16 + fr;
            const float scn = sc[n], shn = sh[n];
            if constexpr (MODE == 1) {
                const int b = mbase / 196;
                const int nn = mbase - b * 196;
                const int hd = n >> 4, cc = n & 15;
                const size_t bh = (size_t)(b * 8 + hd);
#pragma unroll
                for (int r = 0; r < 4; ++r) {
                    float y = acc[nf][r] * scn + shn;
                    ((f16*)OutA)[(bh * NQP + nn + r) * 16 + cc] = (f16)y;
                }
            } else {
#pragma unroll
                for (int r = 0; r < 4; ++r) {
                    float y = acc[nf][r] * scn + shn;
                    ((float*)OutA)[(size_t)(mbase + r) * 384 + n] = y;
                }
            }
        }

        if (c + 1 < NCH) {
            Wl[cur ^ 1][0 * 256 + t] = nx0;
            if constexpr (SR > 1)
                Wl[cur ^ 1][1 * 256 + t] = nx1;
            if constexpr (SR > 2) {
                Wl[cur ^ 1][2 * 256 + t] = nx2;
                Wl[cur ^ 1][3 * 256 + t] = nx3;
            }
            __syncthreads();
            cur ^= 1;
        }
    }
}

// ---------------- fused attention: block = (b,h), 7 waves = 7 q-tiles ----------------
// f16 bias cvt'd into QK MFMA C operand; slot-permuted V (lane's own p = PV A-fragment);
// 2-deep pipeline with unroll-2 (register rotation kills the f32x16 copy); setprio on PV.
__global__ __launch_bounds__(448) void attn_fused(const f16* __restrict__ kb,
                                                  const f16* __restrict__ vtb,
                                                  const f16* __restrict__ qw,
                                                  const f16* __restrict__ biasS,
                                                  f16* __restrict__ ao) {
    const int bh = blockIdx.x;                 // bh%8 = h -> natural XCD pinning per h
    const int b = bh >> 3, h = bh & 7;
    const int wid = threadIdx.x >> 6;          // q-tile 0..6
    const int lane = threadIdx.x & 63;
    const int l31 = lane & 31;
    const int hh = lane >> 5;
    const int q0 = wid * 32;

    const f16x8 bq = *(const f16x8*)(qw + ((size_t)bh * NQP + q0 + l31) * 16 + hh * 8);
    const f16* kpp = kb + (size_t)bh * (NKEYP * 16) + (size_t)l31 * 16 + hh * 8;
    const f16* cbp = biasS + ((size_t)(h * 7 + wid) * 25 * 64 + lane) * 16;
    const f16* vkb = vtb + (size_t)bh * 51200 + l31 * 16 + hh * 8;

    float mrun = -1e30f;
    float lsum = 0.f;
    f32x16 o0 = z16(), o1 = z16();

    // prologue: QK for keyblock 0
    f32x16 sn;
    {
        const f16x8* bp = (const f16x8*)cbp;
        f16x8 b0 = bp[0], b1 = bp[1];
        f32x16 ci;
#pragma unroll
        for (int r = 0; r < 8; ++r) { ci[r] = (float)b0[r]; ci[8 + r] = (float)b1[r]; }
        sn = mfma32(*(const f16x8*)kpp, bq, ci);
    }

#pragma unroll 2
    for (int kbi = 0; kbi < 25; ++kbi) {
        f32x16 s = sn;
        // stage next keyblock: loads + QK MFMA (hide under current softmax)
        if (kbi + 1 < 25) {
            kpp += 512; cbp += 1024;
            const f16x8* bp = (const f16x8*)cbp;
            f16x8 b0 = bp[0], b1 = bp[1];
            f32x16 ci;
#pragma unroll
            for (int r = 0; r < 8; ++r) { ci[r] = (float)b0[r]; ci[8 + r] = (float)b1[r]; }
            sn = mfma32(*(const f16x8*)kpp, bq, ci);
        }
        // V loads for current keyblock (independent, issue early)
        f16x8 bv00 = *(const f16x8*)(vkb);
        f16x8 bv01 = *(const f16x8*)(vkb + 512);
        f16x8 bv10 = *(const f16x8*)(vkb + 1024);
        f16x8 bv11 = *(const f16x8*)(vkb + 1536);
        vkb += 2048;

        float m0v = fmaxf(fmaxf(s[0], s[1]), fmaxf(s[2], s[3]));
        float m1v = fmaxf(fmaxf(s[4], s[5]), fmaxf(s[6], s[7]));
        float m2v = fmaxf(fmaxf(s[8], s[9]), fmaxf(s[10], s[11]));
        float m3v = fmaxf(fmaxf(s[12], s[13]), fmaxf(s[14], s[15]));
        float cmax = fmaxf(fmaxf(m0v, m1v), fmaxf(m2v, m3v));
        cmax = fmaxf(cmax, __shfl_xor(cmax, 32));
        if (__any(cmax > mrun + THR2)) {          // defer-max (log2 domain)
            float mnew = fmaxf(mrun, cmax);
            float f = exp2f(mrun - mnew);
            mrun = mnew;
            lsum *= f;
#pragma unroll
            for (int r = 0; r < 16; ++r) {
                const int cr = (r & 3) + ((r >> 2) << 3) + (hh << 2);
                float fr2 = __shfl(f, cr);
                o0[r] *= fr2;
                o1[r] *= fr2;
            }
        }
        float pr[16];
        float psum = 0.f;
#pragma unroll
        for (int r = 0; r < 16; ++r) {
            pr[r] = exp2f(s[r] - mrun);
            psum += pr[r];
        }
        lsum += psum;
        uint4v w0, w1;
        w0[0] = pkrtz(pr[0], pr[1]);   w0[1] = pkrtz(pr[2], pr[3]);
        w0[2] = pkrtz(pr[4], pr[5]);   w0[3] = pkrtz(pr[6], pr[7]);
        w1[0] = pkrtz(pr[8], pr[9]);   w1[1] = pkrtz(pr[10], pr[11]);
        w1[2] = pkrtz(pr[12], pr[13]); w1[3] = pkrtz(pr[14], pr[15]);
        f16x8 pa0 = __builtin_bit_cast(f16x8, w0);   // own keys, sH=0 (slot-matched V)
        f16x8 pa1 = __builtin_bit_cast(f16x8, w1);   // own keys, sH=1
        __builtin_amdgcn_s_setprio(1);
        o0 = mfma32(pa0, bv00, o0);
        o1 = mfma32(pa0, bv01, o1);
        o0 = mfma32(pa1, bv10, o0);
        o1 = mfma32(pa1, bv11, o1);
        __builtin_amdgcn_s_setprio(0);
    }
    lsum += __shfl_xor(lsum, 32);
    const float inv = 1.0f / lsum;
#pragma unroll
    for (int r = 0; r < 16; ++r) {
        const int cr = (r & 3) + ((r >> 2) << 3) + (hh << 2);
        const float iq = __shfl(inv, cr);
        const int qg = q0 + cr;
        if (qg < NQ) {
            float v0 = o0[r] * iq, v1 = o1[r] * iq;
            float h0 = v0 * fminf(fmaxf(v0 + 3.f, 0.f), 6.f) * (1.f / 6.f);
            float h1 = v1 * fminf(fmaxf(v1 + 3.f, 0.f), 6.f) * (1.f / 6.f);
            f16* dst = ao + ((size_t)b * NQ + qg) * 512 + h * 64 + l31;
            dst[0] = (f16)h0;
            dst[32] = (f16)h1;
        }
    }
}

// ---------------- launch ----------------
extern "C" void kernel_launch(void* const* d_in, const int* in_sizes, int n_in,
                              void* d_out, int out_size, void* d_ws, size_t ws_size,
                              hipStream_t stream) {
    (void)n_in; (void)out_size; (void)ws_size;
    const float* hidden = (const float*)d_in[0];
    const float* w_kv   = (const float*)d_in[1];
    const float* w_q    = (const float*)d_in[6];
    const float* w_p    = (const float*)d_in[11];
    const float* biases = (const float*)d_in[16];
    const int*   idxs   = (const int*)d_in[17];
    const int n_off = in_sizes[16] / 8;

    char* ws = (char*)d_ws;
    const size_t OFF_K  = 0;                       //  26,214,400
    const size_t OFF_V  = 26214400;                // 104,857,600
    const size_t OFF_Q  = 131072000;               //   7,340,032
    const size_t OFF_AO = 138412032;               //  25,690,112
    const size_t OFF_W  = 164102144;               //     786,432
    const size_t OFF_SC = 164888576;               //       9,216
    const size_t OFF_BT = 164897792;               //   2,867,200 (f16 bias)
    f16*   kbuf  = (f16*)(ws + OFF_K);
    f16*   vbuf  = (f16*)(ws + OFF_V);
    f16*   qbuf  = (f16*)(ws + OFF_Q);
    f16*   aobuf = (f16*)(ws + OFF_AO);
    f16*   wf16  = (f16*)(ws + OFF_W);
    float* scbuf = (float*)(ws + OFF_SC);
    f16*   btbuf = (f16*)(ws + OFF_BT);

    prep_all<<<7589, 256, 0, stream>>>(
        (const float*)d_in[2], (const float*)d_in[3], (const float*)d_in[4], (const float*)d_in[5],
        (const float*)d_in[7], (const float*)d_in[8], (const float*)d_in[9], (const float*)d_in[10],
        (const float*)d_in[12], (const float*)d_in[13], (const float*)d_in[14], (const float*)d_in[15],
        w_kv, w_q, w_p, biases, idxs, n_off, scbuf, wf16, btbuf, qbuf);
    gemm_db<1><<<dim3(392, 1), 256, 0, stream>>>(hidden, (const f16x8*)(wf16 + 163840), scbuf + 1280, scbuf + 1408, qbuf);
    gemm_kv<<<784, 256, 0, stream>>>(hidden, (const f16x8*)wf16, scbuf, scbuf + 640, kbuf, vbuf);
    attn_fused<<<1024, 448, 0, stream>>>(kbuf, vbuf, qbuf, btbuf, aobuf);
    gemm_db<2><<<dim3(392, 2), 256, 0, stream>>>(aobuf, (const f16x8*)(wf16 + 196608), scbuf + 1536, scbuf + 1920, d_out);
}

// Round 19
// 198.045 us; speedup vs baseline: 1.0252x; 1.0252x over previous
//
#include <hip/hip_runtime.h>

typedef _Float16 f16;
typedef __attribute__((ext_vector_type(2))) _Float16 f16x2;
typedef __attribute__((ext_vector_type(4))) _Float16 f16x4;
typedef __attribute__((ext_vector_type(8))) _Float16 f16x8;
typedef __attribute__((ext_vector_type(4))) float fvec4;
typedef __attribute__((ext_vector_type(4))) float f32x4;
typedef __attribute__((ext_vector_type(16))) float f32x16;
typedef __attribute__((ext_vector_type(4))) unsigned int uint4v;

#define NKEY 784
#define NKEYP 800
#define NQ 196
#define NQP 224
#define LOG2E 1.442695041f
#define SC2   0.360673760f   /* 0.25 * log2(e) */
#define THR2  11.5415603f    /* 8 * log2(e) */

static __device__ __forceinline__ f32x4 mfma16(f16x8 a, f16x8 b, f32x4 c) {
    return __builtin_amdgcn_mfma_f32_16x16x32_f16(a, b, c, 0, 0, 0);
}
static __device__ __forceinline__ f32x16 mfma32(f16x8 a, f16x8 b, f32x16 c) {
    return __builtin_amdgcn_mfma_f32_32x32x16_f16(a, b, c, 0, 0, 0);
}
static __device__ __forceinline__ unsigned pkrtz(float a, float b) {
    return __builtin_bit_cast(unsigned, __builtin_amdgcn_cvt_pkrtz(a, b));
}
static __device__ __forceinline__ f32x16 z16() {
    f32x16 v;
#pragma unroll
    for (int i = 0; i < 16; ++i) v[i] = 0.f;
    return v;
}

// ---------------- merged prep: BN scales | W->f16 k-major | bias gather | q-pad zero ----------------
__global__ void prep_all(const float* __restrict__ kg, const float* __restrict__ kbet,
                         const float* __restrict__ km, const float* __restrict__ kvv,
                         const float* __restrict__ qg, const float* __restrict__ qbet,
                         const float* __restrict__ qm, const float* __restrict__ qv,
                         const float* __restrict__ pg, const float* __restrict__ pbet,
                         const float* __restrict__ pm, const float* __restrict__ pv,
                         const float* __restrict__ wkv, const float* __restrict__ wq,
                         const float* __restrict__ wp, const float* __restrict__ biases,
                         const int* __restrict__ idxs, int n_off,
                         float* __restrict__ sb, f16* __restrict__ wf16,
                         f16* __restrict__ biasS, f16* __restrict__ qbuf) {
    const int blk = blockIdx.x;
    const int t = threadIdx.x;
    if (blk < 5) {                                    // BN scale/shift folding
        int i = blk * 256 + t;
        if (i < 640) {
            float s = kg[i] * rsqrtf(kvv[i] + 1e-5f);
            sb[i] = s; sb[640 + i] = kbet[i] - km[i] * s;
        } else if (i < 768) {
            int j = i - 640;
            float s = qg[j] * rsqrtf(qv[j] + 1e-5f);
            sb[1280 + j] = s * SC2;                   // q pre-scaled: logits in log2 units
            sb[1408 + j] = (qbet[j] - qm[j] * s) * SC2;
        } else if (i < 1152) {
            int j = i - 768;
            float s = pg[j] * rsqrtf(pv[j] + 1e-5f);
            sb[1536 + j] = s; sb[1920 + j] = pbet[j] - pm[j] * s;
        }
    } else if (blk < 197) {                           // weights -> f16, k-major fragments
        int i = (blk - 5) * 256 + t;                  // 49152 threads
        const float* src;
        f16* dst;
        int kc, n, K;
        if (i < 20480)      { int j = i;         kc = j / 640, n = j - kc * 640; src = wkv; dst = wf16 + (size_t)j * 8;          K = 256; }
        else if (i < 24576) { int j = i - 20480; kc = j / 128, n = j - kc * 128; src = wq;  dst = wf16 + 163840 + (size_t)j * 8; K = 256; }
        else                { int j = i - 24576; kc = j / 384, n = j - kc * 384; src = wp;  dst = wf16 + 196608 + (size_t)j * 8; K = 512; }
        const float* s = src + (size_t)n * K + kc * 8;
        fvec4 v0 = *(const fvec4*)s;
        fvec4 v1 = *(const fvec4*)(s + 4);
        f16x8 h;
        h[0] = (f16)v0[0]; h[1] = (f16)v0[1]; h[2] = (f16)v0[2]; h[3] = (f16)v0[3];
        h[4] = (f16)v1[0]; h[5] = (f16)v1[1]; h[6] = (f16)v1[2]; h[7] = (f16)v1[3];
        *(f16x8*)dst = h;
    } else if (blk < 5797) {                          // bias f16, lane-ordered, log2 domain
        int tid = (blk - 197) * 256 + t;              // 1,433,600 threads
        const int r = tid & 15;
        const int lane = (tid >> 4) & 63;
        const int g = tid >> 10;                      // [h][qt][kb]
        const int kbk = g % 25;
        const int tmp = g / 25;
        const int qt = tmp % 7;
        const int h = tmp / 7;
        const int q = qt * 32 + (lane & 31);
        const int key = kbk * 32 + (r & 3) + 8 * (r >> 2) + 4 * (lane >> 5);
        float v;
        if (key >= NKEY)  v = -30000.f;
        else if (q < NQ)  v = biases[h * n_off + idxs[q * NKEY + key]] * LOG2E;
        else              v = 0.f;
        biasS[tid] = (f16)v;
    } else {                                          // zero q buffer (pad rows)
        int idx = (blk - 5797) * 256 + t;             // 458,752 threads x 8 f16
        f16x8 zz;
#pragma unroll
        for (int j = 0; j < 8; ++j) zz[j] = (f16)0.f;
        *(f16x8*)(qbuf + (size_t)idx * 8) = zz;
    }
}

// ---------------- kv GEMM: 512 threads / BM=128, A in regs, W chunks dbuf in LDS ----------------
// (r17 best-known config: grid 784, halved W L2-stream, residency grid-capped ~24 waves/CU)
__global__ __launch_bounds__(512) void gemm_kv(
        const float* __restrict__ Ap, const f16x8* __restrict__ Wg,
        const float* __restrict__ sc, const float* __restrict__ sh,
        f16* __restrict__ OutK, f16* __restrict__ OutV) {
    __shared__ f16x8 Wl[2][1024];                     // 2 x 16 KB

    const int t = threadIdx.x;
    const int lane = t & 63, wid = t >> 6;
    const int fr = lane & 15, kg = lane >> 4;
    const int m0 = blockIdx.x * 128;
    const int mrow = m0 + wid * 16 + fr;

    const float* abase = Ap + (size_t)mrow * 256 + kg * 8;
    f16x8 af[8];
#pragma unroll
    for (int ks = 0; ks < 8; ++ks) {
        fvec4 v0 = *(const fvec4*)(abase + ks * 32);
        fvec4 v1 = *(const fvec4*)(abase + ks * 32 + 4);
        f16x8 hv;
        hv[0] = (f16)v0[0]; hv[1] = (f16)v0[1]; hv[2] = (f16)v0[2]; hv[3] = (f16)v0[3];
        hv[4] = (f16)v1[0]; hv[5] = (f16)v1[1]; hv[6] = (f16)v1[2]; hv[7] = (f16)v1[3];
        af[ks] = hv;
    }

    // prologue: stage chunk 0 (SR=2)
    Wl[0][t]       = Wg[(size_t)(t >> 5) * 640 + (t & 31)];
    Wl[0][t + 512] = Wg[(size_t)((t + 512) >> 5) * 640 + (t & 31)];
    __syncthreads();

    const int rg = kg * 4;
    int cur = 0;
    for (int c = 0; c < 20; ++c) {
        const int n0c = c * 32;

        f16x8 nx0, nx1;
        if (c + 1 < 20) {
            const int n0n = n0c + 32;
            nx0 = Wg[(size_t)(t >> 5) * 640 + n0n + (t & 31)];
            nx1 = Wg[(size_t)((t + 512) >> 5) * 640 + n0n + (t & 31)];
        }

        f32x4 acc0 = (f32x4){0.f, 0.f, 0.f, 0.f};
        f32x4 acc1 = (f32x4){0.f, 0.f, 0.f, 0.f};
#pragma unroll
        for (int ks = 0; ks < 8; ++ks) {
            f16x8 b0 = Wl[cur][(ks * 4 + kg) * 32 + fr];
            f16x8 b1 = Wl[cur][(ks * 4 + kg) * 32 + 16 + fr];
            acc0 = mfma16(af[ks], b0, acc0);
            acc1 = mfma16(af[ks], b1, acc1);
        }

        const int mbase = m0 + wid * 16 + rg;         // 4 consecutive rows, same b (784%4==0)
#pragma unroll
        for (int nf = 0; nf < 2; ++nf) {
            const f32x4 a4 = nf ? acc1 : acc0;
            const int n = n0c + nf * 16 + fr;
            const float scn = sc[n], shn = sh[n];
            const int b = mbase / 784;
            const int nn = mbase - b * 784;
            const int hd = n / 80;
            const int cc = n - hd * 80;
            const size_t bh = (size_t)(b * 8 + hd);
            if (cc < 16) {
#pragma unroll
                for (int r = 0; r < 4; ++r) {
                    float y = a4[r] * scn + shn;
                    OutK[(bh * NKEYP + nn + r) * 16 + cc] = (f16)y;
                }
            } else {
                // V layout [bh][kb][sH][d(64)][slot16]; slot = quartet-swap of key%16
                const int kbk = nn >> 5, sH = (nn >> 4) & 1;
                const int kq = (nn >> 2) & 3;
                const int slot = ((((kq & 1) << 1) | (kq >> 1)) << 2) | (nn & 3);
                f16x4 pv;
#pragma unroll
                for (int r = 0; r < 4; ++r) pv[r] = (f16)(a4[r] * scn + shn);
                *(f16x4*)(OutV + ((bh * 25 + kbk) * 2 + sH) * 1024 + (cc - 16) * 16 + slot) = pv;
            }
        }

        if (c + 1 < 20) {
            Wl[cur ^ 1][t] = nx0;
            Wl[cur ^ 1][t + 512] = nx1;
            __syncthreads();
            cur ^= 1;
        }
    }
}

// ---------------- small GEMMs (q / proj): A in registers, W db in LDS ----------------
// MODE 1: q : CHUNK=32, grid(392,1).  MODE 2: proj : CHUNK=16 (K=512), grid(392,2)
template <int MODE>
__global__ __launch_bounds__(256) void gemm_db(
        const void* __restrict__ Ap, const f16x8* __restrict__ Wg,
        const float* __restrict__ sc, const float* __restrict__ sh,
        void* __restrict__ OutA) {
    constexpr int K     = (MODE == 2) ? 512 : 256;
    constexpr int KS    = K / 32;
    constexpr int CHUNK = (MODE == 2) ? 16 : 32;
    constexpr int NFR   = CHUNK / 16;
    constexpr int NT    = (MODE == 1) ? 128 : 384;
    constexpr int NCH   = (MODE == 1) ? 4 : 12;
    constexpr int UNITS = (K / 8) * CHUNK;
    constexpr int SR    = UNITS / 256;

    __shared__ f16x8 Wl[2][UNITS];

    const int t = threadIdx.x;
    const int lane = t & 63, wid = t >> 6;
    const int fr = lane & 15, kg = lane >> 4;
    const int m0 = blockIdx.x * 64;
    const int nb0 = blockIdx.y * (NCH * CHUNK);
    const int mrow = m0 + wid * 16 + fr;

    size_t arow;
    if constexpr (MODE == 1) {
        int b = mrow / 196, nn = mrow - b * 196;
        arow = (size_t)b * 784 + (nn / 14) * 56 + (nn % 14) * 2;
    } else {
        arow = (size_t)mrow;
    }
    f16x8 af[KS];
#pragma unroll
    for (int ks = 0; ks < KS; ++ks) {
        if constexpr (MODE == 2) {
            af[ks] = *(const f16x8*)((const f16*)Ap + arow * K + ks * 32 + kg * 8);
        } else {
            const float* a = (const float*)Ap + arow * 256 + ks * 32 + kg * 8;
            fvec4 v0 = *(const fvec4*)a;
            fvec4 v1 = *(const fvec4*)(a + 4);
            f16x8 hv;
            hv[0] = (f16)v0[0]; hv[1] = (f16)v0[1]; hv[2] = (f16)v0[2]; hv[3] = (f16)v0[3];
            hv[4] = (f16)v1[0]; hv[5] = (f16)v1[1]; hv[6] = (f16)v1[2]; hv[7] = (f16)v1[3];
            af[ks] = hv;
        }
    }

#pragma unroll
    for (int rr = 0; rr < SR; ++rr) {
        const int idx = rr * 256 + t;
        Wl[0][idx] = Wg[(size_t)(idx / CHUNK) * NT + nb0 + (idx % CHUNK)];
    }
    __syncthreads();

    const int rg = kg * 4;
    int cur = 0;
    for (int c = 0; c < NCH; ++c) {
        const int n0c = nb0 + c * CHUNK;

        f16x8 nx0, nx1, nx2, nx3;
        if (c + 1 < NCH) {
            const int n0n = n0c + CHUNK;
            nx0 = Wg[(size_t)((0 * 256 + t) / CHUNK) * NT + n0n + ((0 * 256 + t) % CHUNK)];
            if constexpr (SR > 1)
                nx1 = Wg[(size_t)((1 * 256 + t) / CHUNK) * NT + n0n + ((1 * 256 + t) % CHUNK)];
            if constexpr (SR > 2) {
                nx2 = Wg[(size_t)((2 * 256 + t) / CHUNK) * NT + n0n + ((2 * 256 + t) % CHUNK)];
                nx3 = Wg[(size_t)((3 * 256 + t) / CHUNK) * NT + n0n + ((3 * 256 + t) % CHUNK)];
            }
        }

        f32x4 acc[NFR];
#pragma unroll
        for (int j = 0; j < NFR; ++j) acc[j] = (f32x4){0.f, 0.f, 0.f, 0.f};
#pragma unroll
        for (int ks = 0; ks < KS; ++ks) {
            f16x8 bfr[NFR];
#pragma unroll
            for (int nf = 0; nf < NFR; ++nf)
                bfr[nf] = Wl[cur][(ks * 4 + kg) * CHUNK + nf * 16 + fr];
#pragma unroll
            for (int nf = 0; nf < NFR; ++nf)
                acc[nf] = mfma16(af[ks], bfr[nf], acc[nf]);
        }

        const int mbase = m0 + wid * 16 + rg;
#pragma unroll
        for (int nf = 0; nf < NFR; ++nf) {
            const int n = n0c + nf * 16 + fr;
            const float scn = sc[n], shn = sh[n];
            if constexpr (MODE == 1) {
                const int b = mbase / 196;
                const int nn = mbase - b * 196;
                const int hd = n >> 4, cc = n & 15;
                const size_t bh = (size_t)(b * 8 + hd);
#pragma unroll
                for (int r = 0; r < 4; ++r) {
                    float y = acc[nf][r] * scn + shn;
                    ((f16*)OutA)[(bh * NQP + nn + r) * 16 + cc] = (f16)y;
                }
            } else {
#pragma unroll
                for (int r = 0; r < 4; ++r) {
                    float y = acc[nf][r] * scn + shn;
                    ((float*)OutA)[(size_t)(mbase + r) * 384 + n] = y;
                }
            }
        }

        if (c + 1 < NCH) {
            Wl[cur ^ 1][0 * 256 + t] = nx0;
            if constexpr (SR > 1)
                Wl[cur ^ 1][1 * 256 + t] = nx1;
            if constexpr (SR > 2) {
                Wl[cur ^ 1][2 * 256 + t] = nx2;
                Wl[cur ^ 1][3 * 256 + t] = nx3;
            }
            __syncthreads();
            cur ^= 1;
        }
    }
}

// ---------------- fused attention: block = (b,h), 7 waves = 7 q-tiles ----------------
// Branchless 2-deep pipeline: prefetch is UNCONDITIONAL (last iteration recomputes
// keyblock 24, discarded) so the compiler can register-rotate across unroll-2 and
// elide the f32x16 s=sn copies that the old conditional forced.
__global__ __launch_bounds__(448) void attn_fused(const f16* __restrict__ kb,
                                                  const f16* __restrict__ vtb,
                                                  const f16* __restrict__ qw,
                                                  const f16* __restrict__ biasS,
                                                  f16* __restrict__ ao) {
    const int bh = blockIdx.x;                 // bh%8 = h -> natural XCD pinning per h
    const int b = bh >> 3, h = bh & 7;
    const int wid = threadIdx.x >> 6;          // q-tile 0..6
    const int lane = threadIdx.x & 63;
    const int l31 = lane & 31;
    const int hh = lane >> 5;
    const int q0 = wid * 32;

    const f16x8 bq = *(const f16x8*)(qw + ((size_t)bh * NQP + q0 + l31) * 16 + hh * 8);
    const f16* kpp = kb + (size_t)bh * (NKEYP * 16) + (size_t)l31 * 16 + hh * 8;
    const f16* cbp = biasS + ((size_t)(h * 7 + wid) * 25 * 64 + lane) * 16;
    const f16* vkb = vtb + (size_t)bh * 51200 + l31 * 16 + hh * 8;

    float mrun = -1e30f;
    float lsum = 0.f;
    f32x16 o0 = z16(), o1 = z16();

    // prologue: QK for keyblock 0
    f32x16 sn;
    {
        const f16x8* bp = (const f16x8*)cbp;
        f16x8 b0 = bp[0], b1 = bp[1];
        f32x16 ci;
#pragma unroll
        for (int r = 0; r < 8; ++r) { ci[r] = (float)b0[r]; ci[8 + r] = (float)b1[r]; }
        sn = mfma32(*(const f16x8*)kpp, bq, ci);
    }

#pragma unroll 2
    for (int kbi = 0; kbi < 25; ++kbi) {
        f32x16 s = sn;
        // branchless prefetch of next keyblock (kbi==24 recomputes kb24; discarded)
        const int adv = (kbi < 24) ? 1 : 0;
        kpp += adv * 512;
        cbp += adv * 1024;
        {
            const f16x8* bp = (const f16x8*)cbp;
            f16x8 b0 = bp[0], b1 = bp[1];
            f32x16 ci;
#pragma unroll
            for (int r = 0; r < 8; ++r) { ci[r] = (float)b0[r]; ci[8 + r] = (float)b1[r]; }
            sn = mfma32(*(const f16x8*)kpp, bq, ci);
        }
        // V loads for current keyblock (independent, issue early)
        f16x8 bv00 = *(const f16x8*)(vkb);
        f16x8 bv01 = *(const f16x8*)(vkb + 512);
        f16x8 bv10 = *(const f16x8*)(vkb + 1024);
        f16x8 bv11 = *(const f16x8*)(vkb + 1536);
        vkb += 2048;

        float m0v = fmaxf(fmaxf(s[0], s[1]), fmaxf(s[2], s[3]));
        float m1v = fmaxf(fmaxf(s[4], s[5]), fmaxf(s[6], s[7]));
        float m2v = fmaxf(fmaxf(s[8], s[9]), fmaxf(s[10], s[11]));
        float m3v = fmaxf(fmaxf(s[12], s[13]), fmaxf(s[14], s[15]));
        float cmax = fmaxf(fmaxf(m0v, m1v), fmaxf(m2v, m3v));
        cmax = fmaxf(cmax, __shfl_xor(cmax, 32));
        if (__any(cmax > mrun + THR2)) {          // defer-max (log2 domain)
            float mnew = fmaxf(mrun, cmax);
            float f = exp2f(mrun - mnew);
            mrun = mnew;
            lsum *= f;
#pragma unroll
            for (int r = 0; r < 16; ++r) {
                const int cr = (r & 3) + ((r >> 2) << 3) + (hh << 2);
                float fr2 = __shfl(f, cr);
                o0[r] *= fr2;
                o1[r] *= fr2;
            }
        }
        float pr[16];
        float psum = 0.f;
#pragma unroll
        for (int r = 0; r < 16; ++r) {
            pr[r] = exp2f(s[r] - mrun);
            psum += pr[r];
        }
        lsum += psum;
        uint4v w0, w1;
        w0[0] = pkrtz(pr[0], pr[1]);   w0[1] = pkrtz(pr[2], pr[3]);
        w0[2] = pkrtz(pr[4], pr[5]);   w0[3] = pkrtz(pr[6], pr[7]);
        w1[0] = pkrtz(pr[8], pr[9]);   w1[1] = pkrtz(pr[10], pr[11]);
        w1[2] = pkrtz(pr[12], pr[13]); w1[3] = pkrtz(pr[14], pr[15]);
        f16x8 pa0 = __builtin_bit_cast(f16x8, w0);   // own keys, sH=0 (slot-matched V)
        f16x8 pa1 = __builtin_bit_cast(f16x8, w1);   // own keys, sH=1
        __builtin_amdgcn_s_setprio(1);
        o0 = mfma32(pa0, bv00, o0);
        o1 = mfma32(pa0, bv01, o1);
        o0 = mfma32(pa1, bv10, o0);
        o1 = mfma32(pa1, bv11, o1);
        __builtin_amdgcn_s_setprio(0);
    }
    lsum += __shfl_xor(lsum, 32);
    const float inv = 1.0f / lsum;
#pragma unroll
    for (int r = 0; r < 16; ++r) {
        const int cr = (r & 3) + ((r >> 2) << 3) + (hh << 2);
        const float iq = __shfl(inv, cr);
        const int qg = q0 + cr;
        if (qg < NQ) {
            float v0 = o0[r] * iq, v1 = o1[r] * iq;
            float h0 = v0 * fminf(fmaxf(v0 + 3.f, 0.f), 6.f) * (1.f / 6.f);
            float h1 = v1 * fminf(fmaxf(v1 + 3.f, 0.f), 6.f) * (1.f / 6.f);
            f16* dst = ao + ((size_t)b * NQ + qg) * 512 + h * 64 + l31;
            dst[0] = (f16)h0;
            dst[32] = (f16)h1;
        }
    }
}

// ---------------- launch ----------------
extern "C" void kernel_launch(void* const* d_in, const int* in_sizes, int n_in,
                              void* d_out, int out_size, void* d_ws, size_t ws_size,
                              hipStream_t stream) {
    (void)n_in; (void)out_size; (void)ws_size;
    const float* hidden = (const float*)d_in[0];
    const float* w_kv   = (const float*)d_in[1];
    const float* w_q    = (const float*)d_in[6];
    const float* w_p    = (const float*)d_in[11];
    const float* biases = (const float*)d_in[16];
    const int*   idxs   = (const int*)d_in[17];
    const int n_off = in_sizes[16] / 8;

    char* ws = (char*)d_ws;
    const size_t OFF_K  = 0;                       //  26,214,400
    const size_t OFF_V  = 26214400;                // 104,857,600
    const size_t OFF_Q  = 131072000;               //   7,340,032
    const size_t OFF_AO = 138412032;               //  25,690,112
    const size_t OFF_W  = 164102144;               //     786,432
    const size_t OFF_SC = 164888576;               //       9,216
    const size_t OFF_BT = 164897792;               //   2,867,200 (f16 bias)
    f16*   kbuf  = (f16*)(ws + OFF_K);
    f16*   vbuf  = (f16*)(ws + OFF_V);
    f16*   qbuf  = (f16*)(ws + OFF_Q);
    f16*   aobuf = (f16*)(ws + OFF_AO);
    f16*   wf16  = (f16*)(ws + OFF_W);
    float* scbuf = (float*)(ws + OFF_SC);
    f16*   btbuf = (f16*)(ws + OFF_BT);

    prep_all<<<7589, 256, 0, stream>>>(
        (const float*)d_in[2], (const float*)d_in[3], (const float*)d_in[4], (const float*)d_in[5],
        (const float*)d_in[7], (const float*)d_in[8], (const float*)d_in[9], (const float*)d_in[10],
        (const float*)d_in[12], (const float*)d_in[13], (const float*)d_in[14], (const float*)d_in[15],
        w_kv, w_q, w_p, biases, idxs, n_off, scbuf, wf16, btbuf, qbuf);
    gemm_db<1><<<dim3(392, 1), 256, 0, stream>>>(hidden, (const f16x8*)(wf16 + 163840), scbuf + 1280, scbuf + 1408, qbuf);
    gemm_kv<<<784, 512, 0, stream>>>(hidden, (const f16x8*)wf16, scbuf, scbuf + 640, kbuf, vbuf);
    attn_fused<<<1024, 448, 0, stream>>>(kbuf, vbuf, qbuf, btbuf, aobuf);
    gemm_db<2><<<dim3(392, 2), 256, 0, stream>>>(aobuf, (const f16x8*)(wf16 + 196608), scbuf + 1536, scbuf + 1920, d_out);
}